// Round 6
// baseline (547.722 us; speedup 1.0000x reference)
//
#include <hip/hip_runtime.h>
#include <hip/hip_bf16.h>
#include <cstdint>

#define NN 50000
#define TT 8
#define DD 256
#define HH 128
#define EE 800000

typedef float f32x4 __attribute__((ext_vector_type(4)));
typedef short s16x8 __attribute__((ext_vector_type(8)));

struct __align__(8) Edge { int s; float w; };

__device__ inline unsigned short f2bf(float f) {
    union { float f; unsigned u; } c; c.f = f;
    unsigned r = c.u + 0x7FFF + ((c.u >> 16) & 1);
    return (unsigned short)(r >> 16);
}
__device__ inline float bf2f(unsigned short h) {
    union { unsigned u; float f; } c; c.u = ((unsigned)h) << 16;
    return c.f;
}
__device__ inline float4 u4tof4(ushort4 v) {
    return make_float4(bf2f(v.x), bf2f(v.y), bf2f(v.z), bf2f(v.w));
}

// ---------------- weight pre-swizzle: fragment-ready bf16 B layout ----------------
__global__ __launch_bounds__(256) void k_prew(
    const float* __restrict__ Wac, const float* __restrict__ Wao,
    const float* __restrict__ Wc,  const float* __restrict__ Wo,
    short* __restrict__ Bsw1, short* __restrict__ Bsw2)
{
    int t = blockIdx.x * 256 + threadIdx.x;       // 0..16383
    int mat = t >> 13;
    int r = t & 8191;
    int kt = r >> 10;
    int ct = (r >> 6) & 15;
    int lane = r & 63;
    int g = lane >> 4, lr = lane & 15;
    const float* W = mat ? (ct < 8 ? Wc : Wo) : (ct < 8 ? Wac : Wao);
    int c = (ct & 7) * 16 + lr;
    short* out = (mat ? Bsw2 : Bsw1) + ((size_t)((kt * 16 + ct) * 64 + lane)) * 8;
    #pragma unroll
    for (int j = 0; j < 8; ++j) {
        int k = kt * 32 + g * 8 + j;
        out[j] = (short)f2bf(W[k * HH + c]);
    }
}

// ---------------- fused attention (MFMA, LDS-staged, aliased LDS, 4 blocks/CU) ----------------
// block: 8 nodes = 64 rows of x[N*T, 256]. 4 waves; wave w owns rows w*16..w*16+15.
__global__ __launch_bounds__(256, 4) void k_att4(
    const float* __restrict__ x,
    const short* __restrict__ Bsw1, const short* __restrict__ Bsw2,
    const float* __restrict__ bac, const float* __restrict__ vac,
    const float* __restrict__ bao, const float* __restrict__ vao,
    unsigned short* __restrict__ cpo_bf)
{
    __shared__ __align__(16) char smem[33792];
    short* xs = (short*)smem;                    // 32 KB bf16, XOR-16B swizzled
    float* e_lds  = (float*)(smem + 32768);      // [2][64] logits
    float* av_lds = (float*)(smem + 33280);      // [2][64] softmax coeffs
    short* PL = (short*)smem;                    // aliases xs after pooling reads
    unsigned short* cob = (unsigned short*)(smem + 8192);  // GEMM2 staging (alias)

    const int tid = threadIdx.x;
    const int w = tid >> 6, lane = tid & 63;
    const int lr = lane & 15, g = lane >> 4;

    // ---- stage 64 rows of x to LDS as bf16 (coalesced, all loads in flight) ----
    {
        const float* xb = x + (size_t)blockIdx.x * (64 * 256);
        float4 va[8], vb[8];
        #pragma unroll
        for (int k = 0; k < 8; ++k) {
            int u = k * 256 + tid;                  // 8-float unit index
            const float4* p = (const float4*)(xb + (size_t)u * 8);
            va[k] = p[0]; vb[k] = p[1];
        }
        #pragma unroll
        for (int k = 0; k < 8; ++k) {
            int u = k * 256 + tid;
            int row = u >> 5, cu = u & 31;
            s16x8 s;
            s[0] = (short)f2bf(va[k].x); s[1] = (short)f2bf(va[k].y);
            s[2] = (short)f2bf(va[k].z); s[3] = (short)f2bf(va[k].w);
            s[4] = (short)f2bf(vb[k].x); s[5] = (short)f2bf(vb[k].y);
            s[6] = (short)f2bf(vb[k].z); s[7] = (short)f2bf(vb[k].w);
            int byte = row * 512 + ((cu * 16) ^ ((row & 7) << 4));
            *(s16x8*)((char*)xs + byte) = s;
        }
    }
    __syncthreads();

    // ---- A fragments from LDS ----
    s16x8 afr[8];
    {
        char* base = (char*)xs + (w * 16 + lr) * 512;
        const int sw = (lr & 7) << 4;
        #pragma unroll
        for (int kt = 0; kt < 8; ++kt)
            afr[kt] = *(const s16x8*)(base + ((kt * 64 + g * 16) ^ sw));
    }

    // ---- GEMM1: h = x @ [Wac|Wao], fused tanh + v-dot epilogue ----
    float ep[2][4];
    #pragma unroll
    for (int h = 0; h < 2; ++h)
        #pragma unroll
        for (int i = 0; i < 4; ++i) ep[h][i] = 0.f;

    const s16x8* B1 = (const s16x8*)Bsw1;
    #pragma unroll
    for (int ct = 0; ct < 16; ++ct) {
        f32x4 acc = {0.f, 0.f, 0.f, 0.f};
        #pragma unroll
        for (int kt = 0; kt < 8; ++kt)
            acc = __builtin_amdgcn_mfma_f32_16x16x32_bf16(afr[kt], B1[(kt * 16 + ct) * 64 + lane], acc, 0, 0, 0);
        const int head = ct >> 3;
        const int jj = (ct & 7) * 16 + lr;
        float bb = head ? bao[jj] : bac[jj];
        float vv = head ? vao[jj] : vac[jj];
        #pragma unroll
        for (int i = 0; i < 4; ++i) {
            float e = __expf(2.f * (acc[i] + bb));
            float t = (e - 1.f) * __builtin_amdgcn_rcpf(e + 1.f);
            ep[head][i] += t * vv;
        }
    }

    // reduce e over the 16 col-lanes (lr), publish per-row logits
    #pragma unroll
    for (int h = 0; h < 2; ++h)
        #pragma unroll
        for (int i = 0; i < 4; ++i) {
            float v = ep[h][i];
            v += __shfl_xor(v, 1); v += __shfl_xor(v, 2);
            v += __shfl_xor(v, 4); v += __shfl_xor(v, 8);
            ep[h][i] = v;
        }
    if (lr == 0) {
        #pragma unroll
        for (int h = 0; h < 2; ++h)
            #pragma unroll
            for (int i = 0; i < 4; ++i)
                e_lds[h * 64 + w * 16 + g * 4 + i] = ep[h][i];
    }
    __syncthreads();

    // ---- softmax coefficients (threads 0..127: one per (head,row)) ----
    if (tid < 128) {
        int h = tid >> 6, row = tid & 63, nb = row & ~7;
        float m = -1e30f;
        #pragma unroll
        for (int u = 0; u < 8; ++u) m = fmaxf(m, e_lds[h * 64 + nb + u]);
        float s = 0.f;
        #pragma unroll
        for (int u = 0; u < 8; ++u) s += __expf(e_lds[h * 64 + nb + u] - m);
        av_lds[h * 64 + row] = __expf(e_lds[h * 64 + row] - m) * __builtin_amdgcn_rcpf(s);
    }
    __syncthreads();

    // ---- pooling from LDS (reads xs), results held in registers ----
    float accp[2][4][2];
    const int d2 = tid & 127;          // col pair (cols 2*d2, 2*d2+1)
    const int nb = (tid >> 7) * 4;     // node base (0 or 4)
    {
        #pragma unroll
        for (int h = 0; h < 2; ++h)
            #pragma unroll
            for (int nn = 0; nn < 4; ++nn) { accp[h][nn][0] = 0.f; accp[h][nn][1] = 0.f; }
        #pragma unroll
        for (int nn = 0; nn < 4; ++nn) {
            const int n = nb + nn;
            #pragma unroll
            for (int t = 0; t < 8; ++t) {
                int row = n * 8 + t;
                unsigned u = *(const unsigned*)((char*)xs + row * 512 + ((d2 * 4) ^ (t << 4)));
                float lo = bf2f((unsigned short)(u & 0xffff));
                float hi = bf2f((unsigned short)(u >> 16));
                float a0 = av_lds[row], a1 = av_lds[64 + row];
                accp[0][nn][0] = fmaf(a0, lo, accp[0][nn][0]);
                accp[0][nn][1] = fmaf(a0, hi, accp[0][nn][1]);
                accp[1][nn][0] = fmaf(a1, lo, accp[1][nn][0]);
                accp[1][nn][1] = fmaf(a1, hi, accp[1][nn][1]);
            }
        }
    }
    __syncthreads();   // all xs reads done; safe to overwrite with PL

    // ---- write pooled bf16 pairs into PL (aliases xs) in A-fragment layout ----
    {
        int col = d2 * 2;
        int kt = col >> 5, gg = (col >> 3) & 3, jp = col & 7;
        #pragma unroll
        for (int h = 0; h < 2; ++h)
            #pragma unroll
            for (int nn = 0; nn < 4; ++nn) {
                int n = nb + nn;
                unsigned pv = (unsigned)f2bf(accp[h][nn][0]) | ((unsigned)f2bf(accp[h][nn][1]) << 16);
                int sidx = (((h * 8 + kt) * 4 + gg) * 8 + n) * 8 + jp;
                *(unsigned*)((char*)PL + sidx * 2) = pv;
            }
    }
    __syncthreads();

    // ---- GEMM2: cob[8 nodes][256] = pooled_{c|o} @ [Wc|Wo] ----
    {
        const int head = w >> 1;           // waves 0,1 -> c cols, 2,3 -> o cols
        s16x8 a2[8];
        #pragma unroll
        for (int kt = 0; kt < 8; ++kt) {
            int sidx = (((head * 8 + kt) * 4 + g) * 8 + (lr & 7)) * 8;
            a2[kt] = *(const s16x8*)((char*)PL + sidx * 2);
        }
        const s16x8* B2 = (const s16x8*)Bsw2;
        #pragma unroll
        for (int c2 = 0; c2 < 4; ++c2) {
            int ct = w * 4 + c2;
            f32x4 acc = {0.f, 0.f, 0.f, 0.f};
            #pragma unroll
            for (int kt = 0; kt < 8; ++kt)
                acc = __builtin_amdgcn_mfma_f32_16x16x32_bf16(a2[kt], B2[(kt * 16 + ct) * 64 + lane], acc, 0, 0, 0);
            if (g < 2) {
                int col = head * 128 + (ct & 7) * 16 + lr;
                #pragma unroll
                for (int i = 0; i < 4; ++i) {
                    int node = g * 4 + i;
                    cob[node * 256 + col] = f2bf(acc[i]);
                }
            }
        }
    }
    __syncthreads();

    // ---- coalesced block write: 8 nodes x 512 B ----
    {
        const size_t base = (size_t)blockIdx.x * 8 * 256;
        ((ushort4*)(cpo_bf + base))[tid * 2]     = ((const ushort4*)cob)[tid * 2];
        ((ushort4*)(cpo_bf + base))[tid * 2 + 1] = ((const ushort4*)cob)[tid * 2 + 1];
    }
}

// ---------------- CSR build ----------------
__global__ void k_count(const int* __restrict__ dst, int* __restrict__ counts) {
    int e = blockIdx.x * 256 + threadIdx.x;
    if (e < EE) atomicAdd(&counts[dst[e]], 1);
}

__global__ __launch_bounds__(1024) void k_scan(const int* __restrict__ counts, int* __restrict__ starts) {
    __shared__ int sdata[1024];
    __shared__ int s_running;
    if (threadIdx.x == 0) s_running = 0;
    __syncthreads();
    const int nChunks = (NN + 1023) / 1024;
    for (int c = 0; c < nChunks; ++c) {
        int i = c * 1024 + threadIdx.x;
        int v = (i < NN) ? counts[i] : 0;
        sdata[threadIdx.x] = v;
        __syncthreads();
        for (int off = 1; off < 1024; off <<= 1) {
            int tv = (threadIdx.x >= off) ? sdata[threadIdx.x - off] : 0;
            __syncthreads();
            sdata[threadIdx.x] += tv;
            __syncthreads();
        }
        int incl = sdata[threadIdx.x];
        int run = s_running;
        __syncthreads();
        if (i < NN) starts[i] = run + incl - v;
        if (threadIdx.x == 1023) s_running = run + incl;
        __syncthreads();
    }
    if (threadIdx.x == 0) starts[NN] = s_running;
}

__global__ void k_fill(const int* __restrict__ src, const int* __restrict__ dst,
                       const float* __restrict__ w, const int* __restrict__ starts,
                       int* __restrict__ cursor, Edge* __restrict__ edges) {
    int e = blockIdx.x * 256 + threadIdx.x;
    if (e >= EE) return;
    int d = dst[e];
    int pos = atomicAdd(&cursor[d], 1);
    Edge ed; ed.s = src[e]; ed.w = w[e];
    edges[starts[d] + pos] = ed;
}

// ---------------- GNN hops (pull, wave-per-node, bf16 rows, 4-deep gather) ----------------
__global__ __launch_bounds__(256) void k_hop1(
    const unsigned short* __restrict__ cpo_bf,
    const int* __restrict__ starts, const Edge* __restrict__ edges,
    unsigned short* __restrict__ g1_bf)
{
    const int lane = threadIdx.x & 63;
    const int node = blockIdx.x * 4 + (threadIdx.x >> 6);
    const int f = lane * 4;
    const int s0 = starts[node];
    const int s1 = starts[node + 1];
    float4 acc = {0.f, 0.f, 0.f, 0.f};
    int i = s0;
    for (; i + 3 < s1; i += 4) {
        Edge eA = edges[i], eB = edges[i + 1], eC = edges[i + 2], eD = edges[i + 3];
        float4 vA = u4tof4(*(const ushort4*)&cpo_bf[(size_t)eA.s * 256 + f]);
        float4 vB = u4tof4(*(const ushort4*)&cpo_bf[(size_t)eB.s * 256 + f]);
        float4 vC = u4tof4(*(const ushort4*)&cpo_bf[(size_t)eC.s * 256 + f]);
        float4 vD = u4tof4(*(const ushort4*)&cpo_bf[(size_t)eD.s * 256 + f]);
        acc.x = fmaf(eA.w, vA.x, fmaf(eB.w, vB.x, fmaf(eC.w, vC.x, fmaf(eD.w, vD.x, acc.x))));
        acc.y = fmaf(eA.w, vA.y, fmaf(eB.w, vB.y, fmaf(eC.w, vC.y, fmaf(eD.w, vD.y, acc.y))));
        acc.z = fmaf(eA.w, vA.z, fmaf(eB.w, vB.z, fmaf(eC.w, vC.z, fmaf(eD.w, vD.z, acc.z))));
        acc.w = fmaf(eA.w, vA.w, fmaf(eB.w, vB.w, fmaf(eC.w, vC.w, fmaf(eD.w, vD.w, acc.w))));
    }
    for (; i < s1; ++i) {
        Edge eA = edges[i];
        float4 vA = u4tof4(*(const ushort4*)&cpo_bf[(size_t)eA.s * 256 + f]);
        acc.x = fmaf(eA.w, vA.x, acc.x);
        acc.y = fmaf(eA.w, vA.y, acc.y);
        acc.z = fmaf(eA.w, vA.z, acc.z);
        acc.w = fmaf(eA.w, vA.w, acc.w);
    }
    ushort4 o;
    o.x = f2bf(acc.x); o.y = f2bf(acc.y); o.z = f2bf(acc.z); o.w = f2bf(acc.w);
    *(ushort4*)&g1_bf[(size_t)node * 256 + f] = o;
}

__global__ __launch_bounds__(256) void k_hop2(
    const unsigned short* __restrict__ g1_bf, const unsigned short* __restrict__ cpo_bf,
    const float* __restrict__ bc, const float* __restrict__ bo,
    const int* __restrict__ starts, const Edge* __restrict__ edges,
    float* __restrict__ out)
{
    const int lane = threadIdx.x & 63;
    const int node = blockIdx.x * 4 + (threadIdx.x >> 6);
    const int f = lane * 4;
    const int s0 = starts[node];
    const int s1 = starts[node + 1];
    float4 acc = {0.f, 0.f, 0.f, 0.f};
    int i = s0;
    for (; i + 3 < s1; i += 4) {
        Edge eA = edges[i], eB = edges[i + 1], eC = edges[i + 2], eD = edges[i + 3];
        float4 vA = u4tof4(*(const ushort4*)&g1_bf[(size_t)eA.s * 256 + f]);
        float4 vB = u4tof4(*(const ushort4*)&g1_bf[(size_t)eB.s * 256 + f]);
        float4 vC = u4tof4(*(const ushort4*)&g1_bf[(size_t)eC.s * 256 + f]);
        float4 vD = u4tof4(*(const ushort4*)&g1_bf[(size_t)eD.s * 256 + f]);
        acc.x = fmaf(eA.w, vA.x, fmaf(eB.w, vB.x, fmaf(eC.w, vC.x, fmaf(eD.w, vD.x, acc.x))));
        acc.y = fmaf(eA.w, vA.y, fmaf(eB.w, vB.y, fmaf(eC.w, vC.y, fmaf(eD.w, vD.y, acc.y))));
        acc.z = fmaf(eA.w, vA.z, fmaf(eB.w, vB.z, fmaf(eC.w, vC.z, fmaf(eD.w, vD.z, acc.z))));
        acc.w = fmaf(eA.w, vA.w, fmaf(eB.w, vB.w, fmaf(eC.w, vC.w, fmaf(eD.w, vD.w, acc.w))));
    }
    for (; i < s1; ++i) {
        Edge eA = edges[i];
        float4 vA = u4tof4(*(const ushort4*)&g1_bf[(size_t)eA.s * 256 + f]);
        acc.x = fmaf(eA.w, vA.x, acc.x);
        acc.y = fmaf(eA.w, vA.y, acc.y);
        acc.z = fmaf(eA.w, vA.z, acc.z);
        acc.w = fmaf(eA.w, vA.w, acc.w);
    }
    float4 r = u4tof4(*(const ushort4*)&cpo_bf[(size_t)node * 256 + f]);
    float4 b = (f < 128) ? *(const float4*)&bc[f] : *(const float4*)&bo[f - 128];
    r.x += acc.x + b.x; r.y += acc.y + b.y; r.z += acc.z + b.z; r.w += acc.w + b.w;
    if (f < 128) {
        *(float4*)&out[(size_t)node * 128 + f] = r;
    } else {
        r.x = fmaxf(r.x, 0.f); r.y = fmaxf(r.y, 0.f);
        r.z = fmaxf(r.z, 0.f); r.w = fmaxf(r.w, 0.f);
        *(float4*)&out[(size_t)NN * 128 + (size_t)node * 128 + (f - 128)] = r;
    }
}

// ---------------- launch ----------------
extern "C" void kernel_launch(void* const* d_in, const int* in_sizes, int n_in,
                              void* d_out, int out_size, void* d_ws, size_t ws_size,
                              hipStream_t stream)
{
    const float* x   = (const float*)d_in[0];
    const int*   ei  = (const int*)d_in[1];
    const float* ew  = (const float*)d_in[2];
    const float* Wac = (const float*)d_in[3];
    const float* bac = (const float*)d_in[4];
    const float* vac = (const float*)d_in[5];
    const float* Wao = (const float*)d_in[6];
    const float* bao = (const float*)d_in[7];
    const float* vao = (const float*)d_in[8];
    const float* Wc  = (const float*)d_in[9];
    const float* bc  = (const float*)d_in[10];
    const float* Wo  = (const float*)d_in[11];
    const float* bo  = (const float*)d_in[12];
    float* out = (float*)d_out;

    char* ws = (char*)d_ws;
    unsigned short* cpo_bf = (unsigned short*)(ws + 0);         // [N][256] bf16 = 25.6 MB
    unsigned short* g1_bf  = (unsigned short*)(ws + 25600000);  // [N][256] bf16 = 25.6 MB
    short* Bsw1   = (short*)(ws + 51200000);     // 128 KB
    short* Bsw2   = (short*)(ws + 51331072);     // 128 KB
    int*   counts = (int*)(ws + 102400000);
    int*   starts = (int*)(ws + 102600064);
    int*   cursor = (int*)(ws + 102800128);
    Edge*  edges  = (Edge*)(ws + 103000192);     // E * 8 B = 6.4 MB, end ~109.4 MB

    const int* src = ei;
    const int* dst = ei + EE;

    hipMemsetAsync(counts, 0, NN * sizeof(int), stream);
    hipMemsetAsync(cursor, 0, NN * sizeof(int), stream);

    k_prew<<<64, 256, 0, stream>>>(Wac, Wao, Wc, Wo, Bsw1, Bsw2);
    k_count<<<(EE + 255) / 256, 256, 0, stream>>>(dst, counts);
    k_scan<<<1, 1024, 0, stream>>>(counts, starts);
    k_fill<<<(EE + 255) / 256, 256, 0, stream>>>(src, dst, ew, starts, cursor, edges);
    k_att4<<<NN / 8, 256, 0, stream>>>(x, Bsw1, Bsw2, bac, vac, bao, vao, cpo_bf);
    k_hop1<<<NN / 4, 256, 0, stream>>>(cpo_bf, starts, edges, g1_bf);
    k_hop2<<<NN / 4, 256, 0, stream>>>(g1_bf, cpo_bf, bc, bo, starts, edges, out);
}

// Round 7
// 453.140 us; speedup vs baseline: 1.2087x; 1.2087x over previous
//
#include <hip/hip_runtime.h>
#include <hip/hip_bf16.h>
#include <cstdint>

#define NN 50000
#define TT 8
#define DD 256
#define HH 128
#define EE 800000

typedef float f32x4 __attribute__((ext_vector_type(4)));
typedef short s16x8 __attribute__((ext_vector_type(8)));

struct __align__(8) Edge { int s; float w; };

__device__ inline unsigned short f2bf(float f) {
    union { float f; unsigned u; } c; c.f = f;
    unsigned r = c.u + 0x7FFF + ((c.u >> 16) & 1);
    return (unsigned short)(r >> 16);
}
__device__ inline float bf2f(unsigned short h) {
    union { unsigned u; float f; } c; c.u = ((unsigned)h) << 16;
    return c.f;
}
__device__ inline float4 u4tof4(ushort4 v) {
    return make_float4(bf2f(v.x), bf2f(v.y), bf2f(v.z), bf2f(v.w));
}

// ---------------- weight pre-swizzle: fragment-ready bf16 B layout ----------------
__global__ __launch_bounds__(256) void k_prew(
    const float* __restrict__ Wac, const float* __restrict__ Wao,
    const float* __restrict__ Wc,  const float* __restrict__ Wo,
    short* __restrict__ Bsw1, short* __restrict__ Bsw2)
{
    int t = blockIdx.x * 256 + threadIdx.x;       // 0..16383
    int mat = t >> 13;
    int r = t & 8191;
    int kt = r >> 10;
    int ct = (r >> 6) & 15;
    int lane = r & 63;
    int g = lane >> 4, lr = lane & 15;
    const float* W = mat ? (ct < 8 ? Wc : Wo) : (ct < 8 ? Wac : Wao);
    int c = (ct & 7) * 16 + lr;
    short* out = (mat ? Bsw2 : Bsw1) + ((size_t)((kt * 16 + ct) * 64 + lane)) * 8;
    #pragma unroll
    for (int j = 0; j < 8; ++j) {
        int k = kt * 32 + g * 8 + j;
        out[j] = (short)f2bf(W[k * HH + c]);
    }
}

// ---------------- fused attention (MFMA, ct-split waves, B in registers) ----------------
// block: 8 nodes = 64 rows. Wave w computes col-tiles ct = w*4..w*4+3 for ALL 64 rows.
__global__ __launch_bounds__(256, 3) void k_att5(
    const float* __restrict__ x,
    const short* __restrict__ Bsw1, const short* __restrict__ Bsw2,
    const float* __restrict__ bac, const float* __restrict__ vac,
    const float* __restrict__ bao, const float* __restrict__ vao,
    unsigned short* __restrict__ cpo_bf)
{
    __shared__ __align__(16) char smem[34304];
    short* xs = (short*)smem;                    // 32 KB bf16, XOR-16B swizzled
    float* part   = (float*)(smem + 32768);      // [4 waves][64 rows] partial v-dots
    float* av_lds = (float*)(smem + 33792);      // [2][64] softmax coeffs
    short* PL = (short*)smem;                    // aliases xs after pooling reads
    unsigned short* cob = (unsigned short*)(smem + 8192);  // GEMM2 staging (alias)

    const int tid = threadIdx.x;
    const int w = tid >> 6, lane = tid & 63;
    const int lr = lane & 15, g = lane >> 4;
    const int h = w >> 1;                        // head this wave's columns belong to

    // ---- stage 64 rows of x to LDS as bf16 (two halves of 8 float4 in flight) ----
    {
        const float* xb = x + (size_t)blockIdx.x * (64 * 256);
        #pragma unroll
        for (int half = 0; half < 2; ++half) {
            float4 va[4], vb[4];
            #pragma unroll
            for (int k = 0; k < 4; ++k) {
                int u = (half * 4 + k) * 256 + tid;
                const float4* p = (const float4*)(xb + (size_t)u * 8);
                va[k] = p[0]; vb[k] = p[1];
            }
            #pragma unroll
            for (int k = 0; k < 4; ++k) {
                int u = (half * 4 + k) * 256 + tid;
                int row = u >> 5, cu = u & 31;
                s16x8 s;
                s[0] = (short)f2bf(va[k].x); s[1] = (short)f2bf(va[k].y);
                s[2] = (short)f2bf(va[k].z); s[3] = (short)f2bf(va[k].w);
                s[4] = (short)f2bf(vb[k].x); s[5] = (short)f2bf(vb[k].y);
                s[6] = (short)f2bf(vb[k].z); s[7] = (short)f2bf(vb[k].w);
                int byte = row * 512 + ((cu * 16) ^ ((row & 7) << 4));
                *(s16x8*)((char*)xs + byte) = s;
            }
        }
    }
    __syncthreads();

    // ---- GEMM1 (ct-split): ep[rt][i] = sum over this wave's 4 cols-tiles of tanh()*v ----
    float ep[4][4];
    #pragma unroll
    for (int rt = 0; rt < 4; ++rt)
        #pragma unroll
        for (int i = 0; i < 4; ++i) ep[rt][i] = 0.f;

    const s16x8* B1 = (const s16x8*)Bsw1;
    const int sw = (lr & 7) << 4;
    #pragma unroll
    for (int p = 0; p < 2; ++p) {
        const int ct0 = w * 4 + p * 2;
        s16x8 b0[8], b1[8];
        #pragma unroll
        for (int kt = 0; kt < 8; ++kt) {
            b0[kt] = B1[(kt * 16 + ct0) * 64 + lane];
            b1[kt] = B1[(kt * 16 + ct0 + 1) * 64 + lane];
        }
        const int jj0 = (w & 1) * 64 + p * 32 + lr;       // in-head col of ct0 for this lane
        const float bb0 = h ? bao[jj0] : bac[jj0];
        const float vv0 = h ? vao[jj0] : vac[jj0];
        const float bb1 = h ? bao[jj0 + 16] : bac[jj0 + 16];
        const float vv1 = h ? vao[jj0 + 16] : vac[jj0 + 16];
        #pragma unroll
        for (int rt = 0; rt < 4; ++rt) {
            char* base = (char*)xs + (rt * 16 + lr) * 512;
            f32x4 acc0 = {0.f, 0.f, 0.f, 0.f}, acc1 = {0.f, 0.f, 0.f, 0.f};
            #pragma unroll
            for (int kt = 0; kt < 8; ++kt) {
                s16x8 a = *(const s16x8*)(base + ((kt * 64 + g * 16) ^ sw));
                acc0 = __builtin_amdgcn_mfma_f32_16x16x32_bf16(a, b0[kt], acc0, 0, 0, 0);
                acc1 = __builtin_amdgcn_mfma_f32_16x16x32_bf16(a, b1[kt], acc1, 0, 0, 0);
            }
            #pragma unroll
            for (int i = 0; i < 4; ++i) {
                float e0 = __expf(2.f * (acc0[i] + bb0));
                float t0 = (e0 - 1.f) * __builtin_amdgcn_rcpf(e0 + 1.f);
                float e1 = __expf(2.f * (acc1[i] + bb1));
                float t1 = (e1 - 1.f) * __builtin_amdgcn_rcpf(e1 + 1.f);
                ep[rt][i] += t0 * vv0 + t1 * vv1;
            }
        }
    }

    // reduce partial v-dots over the 16 col-lanes, publish per (wave,row)
    #pragma unroll
    for (int rt = 0; rt < 4; ++rt)
        #pragma unroll
        for (int i = 0; i < 4; ++i) {
            float v = ep[rt][i];
            v += __shfl_xor(v, 1); v += __shfl_xor(v, 2);
            v += __shfl_xor(v, 4); v += __shfl_xor(v, 8);
            ep[rt][i] = v;
        }
    if (lr == 0) {
        #pragma unroll
        for (int rt = 0; rt < 4; ++rt)
            #pragma unroll
            for (int i = 0; i < 4; ++i)
                part[w * 64 + rt * 16 + g * 4 + i] = ep[rt][i];
    }
    __syncthreads();

    // ---- combine partials + softmax coefficients (threads 0..127: one per (head,row)) ----
    if (tid < 128) {
        int hh = tid >> 6, row = tid & 63, nb = row & ~7;
        float ee[8];
        #pragma unroll
        for (int u = 0; u < 8; ++u)
            ee[u] = part[hh * 128 + nb + u] + part[hh * 128 + 64 + nb + u];
        float m = -1e30f;
        #pragma unroll
        for (int u = 0; u < 8; ++u) m = fmaxf(m, ee[u]);
        float s = 0.f;
        #pragma unroll
        for (int u = 0; u < 8; ++u) s += __expf(ee[u] - m);
        av_lds[hh * 64 + row] = __expf(ee[row & 7] - m) * __builtin_amdgcn_rcpf(s);
    }
    __syncthreads();

    // ---- pooling from LDS (reads xs), results held in registers ----
    float accp[2][4][2];
    const int d2 = tid & 127;          // col pair (cols 2*d2, 2*d2+1)
    const int nb = (tid >> 7) * 4;     // node base (0 or 4)
    {
        #pragma unroll
        for (int hh = 0; hh < 2; ++hh)
            #pragma unroll
            for (int nn = 0; nn < 4; ++nn) { accp[hh][nn][0] = 0.f; accp[hh][nn][1] = 0.f; }
        #pragma unroll
        for (int nn = 0; nn < 4; ++nn) {
            const int n = nb + nn;
            #pragma unroll
            for (int t = 0; t < 8; ++t) {
                int row = n * 8 + t;
                unsigned u = *(const unsigned*)((char*)xs + row * 512 + ((d2 * 4) ^ (t << 4)));
                float lo = bf2f((unsigned short)(u & 0xffff));
                float hi = bf2f((unsigned short)(u >> 16));
                float a0 = av_lds[row], a1 = av_lds[64 + row];
                accp[0][nn][0] = fmaf(a0, lo, accp[0][nn][0]);
                accp[0][nn][1] = fmaf(a0, hi, accp[0][nn][1]);
                accp[1][nn][0] = fmaf(a1, lo, accp[1][nn][0]);
                accp[1][nn][1] = fmaf(a1, hi, accp[1][nn][1]);
            }
        }
    }
    __syncthreads();   // all xs reads done; safe to overwrite with PL

    // ---- write pooled bf16 pairs into PL (aliases xs) in A-fragment layout ----
    {
        int col = d2 * 2;
        int kt = col >> 5, gg = (col >> 3) & 3, jp = col & 7;
        #pragma unroll
        for (int hh = 0; hh < 2; ++hh)
            #pragma unroll
            for (int nn = 0; nn < 4; ++nn) {
                int n = nb + nn;
                unsigned pv = (unsigned)f2bf(accp[hh][nn][0]) | ((unsigned)f2bf(accp[hh][nn][1]) << 16);
                int sidx = (((hh * 8 + kt) * 4 + gg) * 8 + n) * 8 + jp;
                *(unsigned*)((char*)PL + sidx * 2) = pv;
            }
    }
    __syncthreads();

    // ---- GEMM2: cob[8 nodes][256] = pooled_{c|o} @ [Wc|Wo] ----
    {
        const int head = w >> 1;           // waves 0,1 -> c cols, 2,3 -> o cols
        s16x8 a2[8];
        #pragma unroll
        for (int kt = 0; kt < 8; ++kt) {
            int sidx = (((head * 8 + kt) * 4 + g) * 8 + (lr & 7)) * 8;
            a2[kt] = *(const s16x8*)((char*)PL + sidx * 2);
        }
        const s16x8* B2 = (const s16x8*)Bsw2;
        #pragma unroll
        for (int c2 = 0; c2 < 4; ++c2) {
            int ct = w * 4 + c2;
            f32x4 acc = {0.f, 0.f, 0.f, 0.f};
            #pragma unroll
            for (int kt = 0; kt < 8; ++kt)
                acc = __builtin_amdgcn_mfma_f32_16x16x32_bf16(a2[kt], B2[(kt * 16 + ct) * 64 + lane], acc, 0, 0, 0);
            if (g < 2) {
                int col = head * 128 + (ct & 7) * 16 + lr;
                #pragma unroll
                for (int i = 0; i < 4; ++i) {
                    int node = g * 4 + i;
                    cob[node * 256 + col] = f2bf(acc[i]);
                }
            }
        }
    }
    __syncthreads();

    // ---- coalesced block write: 8 nodes x 512 B ----
    {
        const size_t base = (size_t)blockIdx.x * 8 * 256;
        ((ushort4*)(cpo_bf + base))[tid * 2]     = ((const ushort4*)cob)[tid * 2];
        ((ushort4*)(cpo_bf + base))[tid * 2 + 1] = ((const ushort4*)cob)[tid * 2 + 1];
    }
}

// ---------------- CSR build ----------------
__global__ void k_count(const int* __restrict__ dst, int* __restrict__ counts) {
    int e = blockIdx.x * 256 + threadIdx.x;
    if (e < EE) atomicAdd(&counts[dst[e]], 1);
}

__global__ __launch_bounds__(1024) void k_scan(const int* __restrict__ counts, int* __restrict__ starts) {
    __shared__ int sdata[1024];
    __shared__ int s_running;
    if (threadIdx.x == 0) s_running = 0;
    __syncthreads();
    const int nChunks = (NN + 1023) / 1024;
    for (int c = 0; c < nChunks; ++c) {
        int i = c * 1024 + threadIdx.x;
        int v = (i < NN) ? counts[i] : 0;
        sdata[threadIdx.x] = v;
        __syncthreads();
        for (int off = 1; off < 1024; off <<= 1) {
            int tv = (threadIdx.x >= off) ? sdata[threadIdx.x - off] : 0;
            __syncthreads();
            sdata[threadIdx.x] += tv;
            __syncthreads();
        }
        int incl = sdata[threadIdx.x];
        int run = s_running;
        __syncthreads();
        if (i < NN) starts[i] = run + incl - v;
        if (threadIdx.x == 1023) s_running = run + incl;
        __syncthreads();
    }
    if (threadIdx.x == 0) starts[NN] = s_running;
}

__global__ void k_fill(const int* __restrict__ src, const int* __restrict__ dst,
                       const float* __restrict__ w, const int* __restrict__ starts,
                       int* __restrict__ cursor, Edge* __restrict__ edges) {
    int e = blockIdx.x * 256 + threadIdx.x;
    if (e >= EE) return;
    int d = dst[e];
    int pos = atomicAdd(&cursor[d], 1);
    Edge ed; ed.s = src[e]; ed.w = w[e];
    edges[starts[d] + pos] = ed;
}

// ---------------- GNN hops (pull, wave-per-node, bf16 rows, 4-deep gather) ----------------
__global__ __launch_bounds__(256) void k_hop1(
    const unsigned short* __restrict__ cpo_bf,
    const int* __restrict__ starts, const Edge* __restrict__ edges,
    unsigned short* __restrict__ g1_bf)
{
    const int lane = threadIdx.x & 63;
    const int node = blockIdx.x * 4 + (threadIdx.x >> 6);
    const int f = lane * 4;
    const int s0 = starts[node];
    const int s1 = starts[node + 1];
    float4 acc = {0.f, 0.f, 0.f, 0.f};
    int i = s0;
    for (; i + 3 < s1; i += 4) {
        Edge eA = edges[i], eB = edges[i + 1], eC = edges[i + 2], eD = edges[i + 3];
        float4 vA = u4tof4(*(const ushort4*)&cpo_bf[(size_t)eA.s * 256 + f]);
        float4 vB = u4tof4(*(const ushort4*)&cpo_bf[(size_t)eB.s * 256 + f]);
        float4 vC = u4tof4(*(const ushort4*)&cpo_bf[(size_t)eC.s * 256 + f]);
        float4 vD = u4tof4(*(const ushort4*)&cpo_bf[(size_t)eD.s * 256 + f]);
        acc.x = fmaf(eA.w, vA.x, fmaf(eB.w, vB.x, fmaf(eC.w, vC.x, fmaf(eD.w, vD.x, acc.x))));
        acc.y = fmaf(eA.w, vA.y, fmaf(eB.w, vB.y, fmaf(eC.w, vC.y, fmaf(eD.w, vD.y, acc.y))));
        acc.z = fmaf(eA.w, vA.z, fmaf(eB.w, vB.z, fmaf(eC.w, vC.z, fmaf(eD.w, vD.z, acc.z))));
        acc.w = fmaf(eA.w, vA.w, fmaf(eB.w, vB.w, fmaf(eC.w, vC.w, fmaf(eD.w, vD.w, acc.w))));
    }
    for (; i < s1; ++i) {
        Edge eA = edges[i];
        float4 vA = u4tof4(*(const ushort4*)&cpo_bf[(size_t)eA.s * 256 + f]);
        acc.x = fmaf(eA.w, vA.x, acc.x);
        acc.y = fmaf(eA.w, vA.y, acc.y);
        acc.z = fmaf(eA.w, vA.z, acc.z);
        acc.w = fmaf(eA.w, vA.w, acc.w);
    }
    ushort4 o;
    o.x = f2bf(acc.x); o.y = f2bf(acc.y); o.z = f2bf(acc.z); o.w = f2bf(acc.w);
    *(ushort4*)&g1_bf[(size_t)node * 256 + f] = o;
}

__global__ __launch_bounds__(256) void k_hop2(
    const unsigned short* __restrict__ g1_bf, const unsigned short* __restrict__ cpo_bf,
    const float* __restrict__ bc, const float* __restrict__ bo,
    const int* __restrict__ starts, const Edge* __restrict__ edges,
    float* __restrict__ out)
{
    const int lane = threadIdx.x & 63;
    const int node = blockIdx.x * 4 + (threadIdx.x >> 6);
    const int f = lane * 4;
    const int s0 = starts[node];
    const int s1 = starts[node + 1];
    float4 acc = {0.f, 0.f, 0.f, 0.f};
    int i = s0;
    for (; i + 3 < s1; i += 4) {
        Edge eA = edges[i], eB = edges[i + 1], eC = edges[i + 2], eD = edges[i + 3];
        float4 vA = u4tof4(*(const ushort4*)&g1_bf[(size_t)eA.s * 256 + f]);
        float4 vB = u4tof4(*(const ushort4*)&g1_bf[(size_t)eB.s * 256 + f]);
        float4 vC = u4tof4(*(const ushort4*)&g1_bf[(size_t)eC.s * 256 + f]);
        float4 vD = u4tof4(*(const ushort4*)&g1_bf[(size_t)eD.s * 256 + f]);
        acc.x = fmaf(eA.w, vA.x, fmaf(eB.w, vB.x, fmaf(eC.w, vC.x, fmaf(eD.w, vD.x, acc.x))));
        acc.y = fmaf(eA.w, vA.y, fmaf(eB.w, vB.y, fmaf(eC.w, vC.y, fmaf(eD.w, vD.y, acc.y))));
        acc.z = fmaf(eA.w, vA.z, fmaf(eB.w, vB.z, fmaf(eC.w, vC.z, fmaf(eD.w, vD.z, acc.z))));
        acc.w = fmaf(eA.w, vA.w, fmaf(eB.w, vB.w, fmaf(eC.w, vC.w, fmaf(eD.w, vD.w, acc.w))));
    }
    for (; i < s1; ++i) {
        Edge eA = edges[i];
        float4 vA = u4tof4(*(const ushort4*)&g1_bf[(size_t)eA.s * 256 + f]);
        acc.x = fmaf(eA.w, vA.x, acc.x);
        acc.y = fmaf(eA.w, vA.y, acc.y);
        acc.z = fmaf(eA.w, vA.z, acc.z);
        acc.w = fmaf(eA.w, vA.w, acc.w);
    }
    float4 r = u4tof4(*(const ushort4*)&cpo_bf[(size_t)node * 256 + f]);
    float4 b = (f < 128) ? *(const float4*)&bc[f] : *(const float4*)&bo[f - 128];
    r.x += acc.x + b.x; r.y += acc.y + b.y; r.z += acc.z + b.z; r.w += acc.w + b.w;
    if (f < 128) {
        *(float4*)&out[(size_t)node * 128 + f] = r;
    } else {
        r.x = fmaxf(r.x, 0.f); r.y = fmaxf(r.y, 0.f);
        r.z = fmaxf(r.z, 0.f); r.w = fmaxf(r.w, 0.f);
        *(float4*)&out[(size_t)NN * 128 + (size_t)node * 128 + (f - 128)] = r;
    }
}

// ---------------- launch ----------------
extern "C" void kernel_launch(void* const* d_in, const int* in_sizes, int n_in,
                              void* d_out, int out_size, void* d_ws, size_t ws_size,
                              hipStream_t stream)
{
    const float* x   = (const float*)d_in[0];
    const int*   ei  = (const int*)d_in[1];
    const float* ew  = (const float*)d_in[2];
    const float* Wac = (const float*)d_in[3];
    const float* bac = (const float*)d_in[4];
    const float* vac = (const float*)d_in[5];
    const float* Wao = (const float*)d_in[6];
    const float* bao = (const float*)d_in[7];
    const float* vao = (const float*)d_in[8];
    const float* Wc  = (const float*)d_in[9];
    const float* bc  = (const float*)d_in[10];
    const float* Wo  = (const float*)d_in[11];
    const float* bo  = (const float*)d_in[12];
    float* out = (float*)d_out;

    char* ws = (char*)d_ws;
    unsigned short* cpo_bf = (unsigned short*)(ws + 0);         // [N][256] bf16 = 25.6 MB
    unsigned short* g1_bf  = (unsigned short*)(ws + 25600000);  // [N][256] bf16 = 25.6 MB
    short* Bsw1   = (short*)(ws + 51200000);     // 128 KB
    short* Bsw2   = (short*)(ws + 51331072);     // 128 KB
    int*   counts = (int*)(ws + 102400000);
    int*   starts = (int*)(ws + 102600064);
    int*   cursor = (int*)(ws + 102800128);
    Edge*  edges  = (Edge*)(ws + 103000192);     // E * 8 B = 6.4 MB, end ~109.4 MB

    const int* src = ei;
    const int* dst = ei + EE;

    hipMemsetAsync(counts, 0, NN * sizeof(int), stream);
    hipMemsetAsync(cursor, 0, NN * sizeof(int), stream);

    k_prew<<<64, 256, 0, stream>>>(Wac, Wao, Wc, Wo, Bsw1, Bsw2);
    k_count<<<(EE + 255) / 256, 256, 0, stream>>>(dst, counts);
    k_scan<<<1, 1024, 0, stream>>>(counts, starts);
    k_fill<<<(EE + 255) / 256, 256, 0, stream>>>(src, dst, ew, starts, cursor, edges);
    k_att5<<<NN / 8, 256, 0, stream>>>(x, Bsw1, Bsw2, bac, vac, bao, vao, cpo_bf);
    k_hop1<<<NN / 4, 256, 0, stream>>>(cpo_bf, starts, edges, g1_bf);
    k_hop2<<<NN / 4, 256, 0, stream>>>(g1_bf, cpo_bf, bc, bo, starts, edges, out);
}

// Round 8
// 448.215 us; speedup vs baseline: 1.2220x; 1.0110x over previous
//
#include <hip/hip_runtime.h>
#include <hip/hip_bf16.h>
#include <cstdint>

#define NN 50000
#define TT 8
#define DD 256
#define HH 128
#define EE 800000

typedef float f32x4 __attribute__((ext_vector_type(4)));
typedef short s16x8 __attribute__((ext_vector_type(8)));

struct __align__(8) Edge { int s; float w; };

__device__ inline unsigned short f2bf(float f) {
    union { float f; unsigned u; } c; c.f = f;
    unsigned r = c.u + 0x7FFF + ((c.u >> 16) & 1);
    return (unsigned short)(r >> 16);
}
__device__ inline float bf2f(unsigned short h) {
    union { unsigned u; float f; } c; c.u = ((unsigned)h) << 16;
    return c.f;
}

// ---------------- weight pre-swizzle: fragment-ready bf16 B layout ----------------
__global__ __launch_bounds__(256) void k_prew(
    const float* __restrict__ Wac, const float* __restrict__ Wao,
    const float* __restrict__ Wc,  const float* __restrict__ Wo,
    short* __restrict__ Bsw1, short* __restrict__ Bsw2)
{
    int t = blockIdx.x * 256 + threadIdx.x;       // 0..16383
    int mat = t >> 13;
    int r = t & 8191;
    int kt = r >> 10;
    int ct = (r >> 6) & 15;
    int lane = r & 63;
    int g = lane >> 4, lr = lane & 15;
    const float* W = mat ? (ct < 8 ? Wc : Wo) : (ct < 8 ? Wac : Wao);
    int c = (ct & 7) * 16 + lr;
    short* out = (mat ? Bsw2 : Bsw1) + ((size_t)((kt * 16 + ct) * 64 + lane)) * 8;
    #pragma unroll
    for (int j = 0; j < 8; ++j) {
        int k = kt * 32 + g * 8 + j;
        out[j] = (short)f2bf(W[k * HH + c]);
    }
}

// ---------------- fused attention (MFMA, ct-split waves, B in registers) ----------------
// block: 8 nodes = 64 rows. Wave w computes col-tiles ct = w*4..w*4+3 for ALL 64 rows.
__global__ __launch_bounds__(256, 3) void k_att5(
    const float* __restrict__ x,
    const short* __restrict__ Bsw1, const short* __restrict__ Bsw2,
    const float* __restrict__ bac, const float* __restrict__ vac,
    const float* __restrict__ bao, const float* __restrict__ vao,
    unsigned short* __restrict__ cpo_bf)
{
    __shared__ __align__(16) char smem[34304];
    short* xs = (short*)smem;                    // 32 KB bf16, XOR-16B swizzled
    float* part   = (float*)(smem + 32768);      // [4 waves][64 rows] partial v-dots
    float* av_lds = (float*)(smem + 33792);      // [2][64] softmax coeffs
    short* PL = (short*)smem;                    // aliases xs after pooling reads
    unsigned short* cob = (unsigned short*)(smem + 8192);  // GEMM2 staging (alias)

    const int tid = threadIdx.x;
    const int w = tid >> 6, lane = tid & 63;
    const int lr = lane & 15, g = lane >> 4;
    const int h = w >> 1;                        // head this wave's columns belong to

    // ---- stage 64 rows of x to LDS as bf16 (two halves of 8 float4 in flight) ----
    {
        const float* xb = x + (size_t)blockIdx.x * (64 * 256);
        #pragma unroll
        for (int half = 0; half < 2; ++half) {
            float4 va[4], vb[4];
            #pragma unroll
            for (int k = 0; k < 4; ++k) {
                int u = (half * 4 + k) * 256 + tid;
                const float4* p = (const float4*)(xb + (size_t)u * 8);
                va[k] = p[0]; vb[k] = p[1];
            }
            #pragma unroll
            for (int k = 0; k < 4; ++k) {
                int u = (half * 4 + k) * 256 + tid;
                int row = u >> 5, cu = u & 31;
                s16x8 s;
                s[0] = (short)f2bf(va[k].x); s[1] = (short)f2bf(va[k].y);
                s[2] = (short)f2bf(va[k].z); s[3] = (short)f2bf(va[k].w);
                s[4] = (short)f2bf(vb[k].x); s[5] = (short)f2bf(vb[k].y);
                s[6] = (short)f2bf(vb[k].z); s[7] = (short)f2bf(vb[k].w);
                int byte = row * 512 + ((cu * 16) ^ ((row & 7) << 4));
                *(s16x8*)((char*)xs + byte) = s;
            }
        }
    }
    __syncthreads();

    // ---- GEMM1 (ct-split): ep[rt][i] = sum over this wave's 4 col-tiles of tanh()*v ----
    float ep[4][4];
    #pragma unroll
    for (int rt = 0; rt < 4; ++rt)
        #pragma unroll
        for (int i = 0; i < 4; ++i) ep[rt][i] = 0.f;

    const s16x8* B1 = (const s16x8*)Bsw1;
    const int sw = (lr & 7) << 4;
    #pragma unroll
    for (int p = 0; p < 2; ++p) {
        const int ct0 = w * 4 + p * 2;
        s16x8 b0[8], b1[8];
        #pragma unroll
        for (int kt = 0; kt < 8; ++kt) {
            b0[kt] = B1[(kt * 16 + ct0) * 64 + lane];
            b1[kt] = B1[(kt * 16 + ct0 + 1) * 64 + lane];
        }
        const int jj0 = (w & 1) * 64 + p * 32 + lr;       // in-head col of ct0 for this lane
        const float bb0 = h ? bao[jj0] : bac[jj0];
        const float vv0 = h ? vao[jj0] : vac[jj0];
        const float bb1 = h ? bao[jj0 + 16] : bac[jj0 + 16];
        const float vv1 = h ? vao[jj0 + 16] : vac[jj0 + 16];
        #pragma unroll
        for (int rt = 0; rt < 4; ++rt) {
            char* base = (char*)xs + (rt * 16 + lr) * 512;
            f32x4 acc0 = {0.f, 0.f, 0.f, 0.f}, acc1 = {0.f, 0.f, 0.f, 0.f};
            #pragma unroll
            for (int kt = 0; kt < 8; ++kt) {
                s16x8 a = *(const s16x8*)(base + ((kt * 64 + g * 16) ^ sw));
                acc0 = __builtin_amdgcn_mfma_f32_16x16x32_bf16(a, b0[kt], acc0, 0, 0, 0);
                acc1 = __builtin_amdgcn_mfma_f32_16x16x32_bf16(a, b1[kt], acc1, 0, 0, 0);
            }
            #pragma unroll
            for (int i = 0; i < 4; ++i) {
                float e0 = __expf(2.f * (acc0[i] + bb0));
                float t0 = (e0 - 1.f) * __builtin_amdgcn_rcpf(e0 + 1.f);
                float e1 = __expf(2.f * (acc1[i] + bb1));
                float t1 = (e1 - 1.f) * __builtin_amdgcn_rcpf(e1 + 1.f);
                ep[rt][i] += t0 * vv0 + t1 * vv1;
            }
        }
    }

    // reduce partial v-dots over the 16 col-lanes, publish per (wave,row)
    #pragma unroll
    for (int rt = 0; rt < 4; ++rt)
        #pragma unroll
        for (int i = 0; i < 4; ++i) {
            float v = ep[rt][i];
            v += __shfl_xor(v, 1); v += __shfl_xor(v, 2);
            v += __shfl_xor(v, 4); v += __shfl_xor(v, 8);
            ep[rt][i] = v;
        }
    if (lr == 0) {
        #pragma unroll
        for (int rt = 0; rt < 4; ++rt)
            #pragma unroll
            for (int i = 0; i < 4; ++i)
                part[w * 64 + rt * 16 + g * 4 + i] = ep[rt][i];
    }
    __syncthreads();

    // ---- combine partials + softmax coefficients (threads 0..127: one per (head,row)) ----
    if (tid < 128) {
        int hh = tid >> 6, row = tid & 63, nb = row & ~7;
        float ee[8];
        #pragma unroll
        for (int u = 0; u < 8; ++u)
            ee[u] = part[hh * 128 + nb + u] + part[hh * 128 + 64 + nb + u];
        float m = -1e30f;
        #pragma unroll
        for (int u = 0; u < 8; ++u) m = fmaxf(m, ee[u]);
        float s = 0.f;
        #pragma unroll
        for (int u = 0; u < 8; ++u) s += __expf(ee[u] - m);
        av_lds[hh * 64 + row] = __expf(ee[row & 7] - m) * __builtin_amdgcn_rcpf(s);
    }
    __syncthreads();

    // ---- pooling from LDS (reads xs), results held in registers ----
    float accp[2][4][2];
    const int d2 = tid & 127;          // col pair (cols 2*d2, 2*d2+1)
    const int nb = (tid >> 7) * 4;     // node base (0 or 4)
    {
        #pragma unroll
        for (int hh = 0; hh < 2; ++hh)
            #pragma unroll
            for (int nn = 0; nn < 4; ++nn) { accp[hh][nn][0] = 0.f; accp[hh][nn][1] = 0.f; }
        #pragma unroll
        for (int nn = 0; nn < 4; ++nn) {
            const int n = nb + nn;
            #pragma unroll
            for (int t = 0; t < 8; ++t) {
                int row = n * 8 + t;
                unsigned u = *(const unsigned*)((char*)xs + row * 512 + ((d2 * 4) ^ (t << 4)));
                float lo = bf2f((unsigned short)(u & 0xffff));
                float hi = bf2f((unsigned short)(u >> 16));
                float a0 = av_lds[row], a1 = av_lds[64 + row];
                accp[0][nn][0] = fmaf(a0, lo, accp[0][nn][0]);
                accp[0][nn][1] = fmaf(a0, hi, accp[0][nn][1]);
                accp[1][nn][0] = fmaf(a1, lo, accp[1][nn][0]);
                accp[1][nn][1] = fmaf(a1, hi, accp[1][nn][1]);
            }
        }
    }
    __syncthreads();   // all xs reads done; safe to overwrite with PL

    // ---- write pooled bf16 pairs into PL (aliases xs) in A-fragment layout ----
    {
        int col = d2 * 2;
        int kt = col >> 5, gg = (col >> 3) & 3, jp = col & 7;
        #pragma unroll
        for (int hh = 0; hh < 2; ++hh)
            #pragma unroll
            for (int nn = 0; nn < 4; ++nn) {
                int n = nb + nn;
                unsigned pv = (unsigned)f2bf(accp[hh][nn][0]) | ((unsigned)f2bf(accp[hh][nn][1]) << 16);
                int sidx = (((hh * 8 + kt) * 4 + gg) * 8 + n) * 8 + jp;
                *(unsigned*)((char*)PL + sidx * 2) = pv;
            }
    }
    __syncthreads();

    // ---- GEMM2: cob[8 nodes][256] = pooled_{c|o} @ [Wc|Wo] ----
    {
        const int head = w >> 1;           // waves 0,1 -> c cols, 2,3 -> o cols
        s16x8 a2[8];
        #pragma unroll
        for (int kt = 0; kt < 8; ++kt) {
            int sidx = (((head * 8 + kt) * 4 + g) * 8 + (lr & 7)) * 8;
            a2[kt] = *(const s16x8*)((char*)PL + sidx * 2);
        }
        const s16x8* B2 = (const s16x8*)Bsw2;
        #pragma unroll
        for (int c2 = 0; c2 < 4; ++c2) {
            int ct = w * 4 + c2;
            f32x4 acc = {0.f, 0.f, 0.f, 0.f};
            #pragma unroll
            for (int kt = 0; kt < 8; ++kt)
                acc = __builtin_amdgcn_mfma_f32_16x16x32_bf16(a2[kt], B2[(kt * 16 + ct) * 64 + lane], acc, 0, 0, 0);
            if (g < 2) {
                int col = head * 128 + (ct & 7) * 16 + lr;
                #pragma unroll
                for (int i = 0; i < 4; ++i) {
                    int node = g * 4 + i;
                    cob[node * 256 + col] = f2bf(acc[i]);
                }
            }
        }
    }
    __syncthreads();

    // ---- coalesced block write: 8 nodes x 512 B ----
    {
        const size_t base = (size_t)blockIdx.x * 8 * 256;
        ((ushort4*)(cpo_bf + base))[tid * 2]     = ((const ushort4*)cob)[tid * 2];
        ((ushort4*)(cpo_bf + base))[tid * 2 + 1] = ((const ushort4*)cob)[tid * 2 + 1];
    }
}

// ---------------- CSR build ----------------
__global__ void k_count(const int* __restrict__ dst, int* __restrict__ counts) {
    int e = blockIdx.x * 256 + threadIdx.x;
    if (e < EE) atomicAdd(&counts[dst[e]], 1);
}

__global__ __launch_bounds__(1024) void k_scan(const int* __restrict__ counts, int* __restrict__ starts) {
    __shared__ int sdata[1024];
    __shared__ int s_running;
    if (threadIdx.x == 0) s_running = 0;
    __syncthreads();
    const int nChunks = (NN + 1023) / 1024;
    for (int c = 0; c < nChunks; ++c) {
        int i = c * 1024 + threadIdx.x;
        int v = (i < NN) ? counts[i] : 0;
        sdata[threadIdx.x] = v;
        __syncthreads();
        for (int off = 1; off < 1024; off <<= 1) {
            int tv = (threadIdx.x >= off) ? sdata[threadIdx.x - off] : 0;
            __syncthreads();
            sdata[threadIdx.x] += tv;
            __syncthreads();
        }
        int incl = sdata[threadIdx.x];
        int run = s_running;
        __syncthreads();
        if (i < NN) starts[i] = run + incl - v;
        if (threadIdx.x == 1023) s_running = run + incl;
        __syncthreads();
    }
    if (threadIdx.x == 0) starts[NN] = s_running;
}

__global__ void k_fill(const int* __restrict__ src, const int* __restrict__ dst,
                       const float* __restrict__ w, const int* __restrict__ starts,
                       int* __restrict__ cursor, Edge* __restrict__ edges) {
    int e = blockIdx.x * 256 + threadIdx.x;
    if (e >= EE) return;
    int d = dst[e];
    int pos = atomicAdd(&cursor[d], 1);
    Edge ed; ed.s = src[e]; ed.w = w[e];
    edges[starts[d] + pos] = ed;
}

// ---------------- GNN hops: half-wave edge parallel, 16 B/lane gathers ----------------
// wave = node; lanes 0-31 even edges, 32-63 odd edges; lane covers 8 cols (ushort8).
__global__ __launch_bounds__(256) void k_hop1(
    const unsigned short* __restrict__ cpo_bf,
    const int* __restrict__ starts, const Edge* __restrict__ edges,
    unsigned short* __restrict__ g1_bf)
{
    const int lane = threadIdx.x & 63;
    const int node = blockIdx.x * 4 + (threadIdx.x >> 6);
    const int half = lane >> 5;
    const int c0 = (lane & 31) * 8;
    const int s0 = starts[node];
    const int s1 = starts[node + 1];
    float acc[8] = {0.f, 0.f, 0.f, 0.f, 0.f, 0.f, 0.f, 0.f};
    int i = s0 + half;
    for (; i + 6 < s1; i += 8) {
        Edge e0 = edges[i], e1 = edges[i + 2], e2 = edges[i + 4], e3 = edges[i + 6];
        s16x8 v0 = *(const s16x8*)&cpo_bf[(size_t)e0.s * 256 + c0];
        s16x8 v1 = *(const s16x8*)&cpo_bf[(size_t)e1.s * 256 + c0];
        s16x8 v2 = *(const s16x8*)&cpo_bf[(size_t)e2.s * 256 + c0];
        s16x8 v3 = *(const s16x8*)&cpo_bf[(size_t)e3.s * 256 + c0];
        #pragma unroll
        for (int j = 0; j < 8; ++j) {
            acc[j] = fmaf(e0.w, bf2f((unsigned short)v0[j]),
                     fmaf(e1.w, bf2f((unsigned short)v1[j]),
                     fmaf(e2.w, bf2f((unsigned short)v2[j]),
                     fmaf(e3.w, bf2f((unsigned short)v3[j]), acc[j]))));
        }
    }
    for (; i < s1; i += 2) {
        Edge e0 = edges[i];
        s16x8 v0 = *(const s16x8*)&cpo_bf[(size_t)e0.s * 256 + c0];
        #pragma unroll
        for (int j = 0; j < 8; ++j)
            acc[j] = fmaf(e0.w, bf2f((unsigned short)v0[j]), acc[j]);
    }
    #pragma unroll
    for (int j = 0; j < 8; ++j) acc[j] += __shfl_xor(acc[j], 32);
    if (half == 0) {
        s16x8 o;
        #pragma unroll
        for (int j = 0; j < 8; ++j) o[j] = (short)f2bf(acc[j]);
        *(s16x8*)&g1_bf[(size_t)node * 256 + c0] = o;
    }
}

__global__ __launch_bounds__(256) void k_hop2(
    const unsigned short* __restrict__ g1_bf, const unsigned short* __restrict__ cpo_bf,
    const float* __restrict__ bc, const float* __restrict__ bo,
    const int* __restrict__ starts, const Edge* __restrict__ edges,
    float* __restrict__ out)
{
    const int lane = threadIdx.x & 63;
    const int node = blockIdx.x * 4 + (threadIdx.x >> 6);
    const int half = lane >> 5;
    const int c0 = (lane & 31) * 8;
    const int s0 = starts[node];
    const int s1 = starts[node + 1];
    float acc[8] = {0.f, 0.f, 0.f, 0.f, 0.f, 0.f, 0.f, 0.f};
    int i = s0 + half;
    for (; i + 6 < s1; i += 8) {
        Edge e0 = edges[i], e1 = edges[i + 2], e2 = edges[i + 4], e3 = edges[i + 6];
        s16x8 v0 = *(const s16x8*)&g1_bf[(size_t)e0.s * 256 + c0];
        s16x8 v1 = *(const s16x8*)&g1_bf[(size_t)e1.s * 256 + c0];
        s16x8 v2 = *(const s16x8*)&g1_bf[(size_t)e2.s * 256 + c0];
        s16x8 v3 = *(const s16x8*)&g1_bf[(size_t)e3.s * 256 + c0];
        #pragma unroll
        for (int j = 0; j < 8; ++j) {
            acc[j] = fmaf(e0.w, bf2f((unsigned short)v0[j]),
                     fmaf(e1.w, bf2f((unsigned short)v1[j]),
                     fmaf(e2.w, bf2f((unsigned short)v2[j]),
                     fmaf(e3.w, bf2f((unsigned short)v3[j]), acc[j]))));
        }
    }
    for (; i < s1; i += 2) {
        Edge e0 = edges[i];
        s16x8 v0 = *(const s16x8*)&g1_bf[(size_t)e0.s * 256 + c0];
        #pragma unroll
        for (int j = 0; j < 8; ++j)
            acc[j] = fmaf(e0.w, bf2f((unsigned short)v0[j]), acc[j]);
    }
    #pragma unroll
    for (int j = 0; j < 8; ++j) acc[j] += __shfl_xor(acc[j], 32);
    if (half == 0) {
        s16x8 cv = *(const s16x8*)&cpo_bf[(size_t)node * 256 + c0];
        float r[8];
        if (c0 < 128) {
            #pragma unroll
            for (int j = 0; j < 8; ++j)
                r[j] = acc[j] + bf2f((unsigned short)cv[j]) + bc[c0 + j];
            float4* o4 = (float4*)&out[(size_t)node * 128 + c0];
            o4[0] = make_float4(r[0], r[1], r[2], r[3]);
            o4[1] = make_float4(r[4], r[5], r[6], r[7]);
        } else {
            #pragma unroll
            for (int j = 0; j < 8; ++j)
                r[j] = fmaxf(acc[j] + bf2f((unsigned short)cv[j]) + bo[c0 - 128 + j], 0.f);
            float4* o4 = (float4*)&out[(size_t)NN * 128 + (size_t)node * 128 + (c0 - 128)];
            o4[0] = make_float4(r[0], r[1], r[2], r[3]);
            o4[1] = make_float4(r[4], r[5], r[6], r[7]);
        }
    }
}

// ---------------- launch ----------------
extern "C" void kernel_launch(void* const* d_in, const int* in_sizes, int n_in,
                              void* d_out, int out_size, void* d_ws, size_t ws_size,
                              hipStream_t stream)
{
    const float* x   = (const float*)d_in[0];
    const int*   ei  = (const int*)d_in[1];
    const float* ew  = (const float*)d_in[2];
    const float* Wac = (const float*)d_in[3];
    const float* bac = (const float*)d_in[4];
    const float* vac = (const float*)d_in[5];
    const float* Wao = (const float*)d_in[6];
    const float* bao = (const float*)d_in[7];
    const float* vao = (const float*)d_in[8];
    const float* Wc  = (const float*)d_in[9];
    const float* bc  = (const float*)d_in[10];
    const float* Wo  = (const float*)d_in[11];
    const float* bo  = (const float*)d_in[12];
    float* out = (float*)d_out;

    char* ws = (char*)d_ws;
    unsigned short* cpo_bf = (unsigned short*)(ws + 0);         // [N][256] bf16 = 25.6 MB
    unsigned short* g1_bf  = (unsigned short*)(ws + 25600000);  // [N][256] bf16 = 25.6 MB
    short* Bsw1   = (short*)(ws + 51200000);     // 128 KB
    short* Bsw2   = (short*)(ws + 51331072);     // 128 KB
    int*   counts = (int*)(ws + 102400000);
    int*   starts = (int*)(ws + 102600064);
    int*   cursor = (int*)(ws + 102800128);
    Edge*  edges  = (Edge*)(ws + 103000192);     // E * 8 B = 6.4 MB, end ~109.4 MB

    const int* src = ei;
    const int* dst = ei + EE;

    hipMemsetAsync(counts, 0, NN * sizeof(int), stream);
    hipMemsetAsync(cursor, 0, NN * sizeof(int), stream);

    k_prew<<<64, 256, 0, stream>>>(Wac, Wao, Wc, Wo, Bsw1, Bsw2);
    k_count<<<(EE + 255) / 256, 256, 0, stream>>>(dst, counts);
    k_scan<<<1, 1024, 0, stream>>>(counts, starts);
    k_fill<<<(EE + 255) / 256, 256, 0, stream>>>(src, dst, ew, starts, cursor, edges);
    k_att5<<<NN / 8, 256, 0, stream>>>(x, Bsw1, Bsw2, bac, vac, bao, vao, cpo_bf);
    k_hop1<<<NN / 4, 256, 0, stream>>>(cpo_bf, starts, edges, g1_bf);
    k_hop2<<<NN / 4, 256, 0, stream>>>(g1_bf, cpo_bf, bc, bo, starts, edges, out);
}

// Round 9
// 419.330 us; speedup vs baseline: 1.3062x; 1.0689x over previous
//
#include <hip/hip_runtime.h>
#include <hip/hip_bf16.h>
#include <cstdint>

#define NN 50000
#define TT 8
#define DD 256
#define HH 128
#define EE 800000

typedef float f32x4 __attribute__((ext_vector_type(4)));
typedef short s16x8 __attribute__((ext_vector_type(8)));
typedef char  s8x8  __attribute__((ext_vector_type(8)));

struct __align__(8) Edge { int s; float w; };

__device__ inline unsigned short f2bf(float f) {
    union { float f; unsigned u; } c; c.f = f;
    unsigned r = c.u + 0x7FFF + ((c.u >> 16) & 1);
    return (unsigned short)(r >> 16);
}
__device__ inline float bf2f(unsigned short h) {
    union { unsigned u; float f; } c; c.u = ((unsigned)h) << 16;
    return c.f;
}

// ---------------- fused: weight pre-swizzle (blocks 0..63) + edge count (rest) ----------------
__global__ __launch_bounds__(256) void k_pc(
    const float* __restrict__ Wac, const float* __restrict__ Wao,
    const float* __restrict__ Wc,  const float* __restrict__ Wo,
    short* __restrict__ Bsw1, short* __restrict__ Bsw2,
    const int* __restrict__ dst, int* __restrict__ counts)
{
    if (blockIdx.x < 64) {
        int t = blockIdx.x * 256 + threadIdx.x;       // 0..16383
        int mat = t >> 13;
        int r = t & 8191;
        int kt = r >> 10;
        int ct = (r >> 6) & 15;
        int lane = r & 63;
        int g = lane >> 4, lr = lane & 15;
        const float* W = mat ? (ct < 8 ? Wc : Wo) : (ct < 8 ? Wac : Wao);
        int c = (ct & 7) * 16 + lr;
        short* out = (mat ? Bsw2 : Bsw1) + ((size_t)((kt * 16 + ct) * 64 + lane)) * 8;
        #pragma unroll
        for (int j = 0; j < 8; ++j) {
            int k = kt * 32 + g * 8 + j;
            out[j] = (short)f2bf(W[k * HH + c]);
        }
    } else {
        int e = (blockIdx.x - 64) * 256 + threadIdx.x;
        if (e < EE) atomicAdd(&counts[dst[e]], 1);
    }
}

// ---------------- fused attention (MFMA, ct-split waves, B in registers) ----------------
// block: 8 nodes = 64 rows. Wave w computes col-tiles ct = w*4..w*4+3 for ALL 64 rows.
__global__ __launch_bounds__(256, 3) void k_att5(
    const float* __restrict__ x,
    const short* __restrict__ Bsw1, const short* __restrict__ Bsw2,
    const float* __restrict__ bac, const float* __restrict__ vac,
    const float* __restrict__ bao, const float* __restrict__ vao,
    unsigned short* __restrict__ cpo_bf, char* __restrict__ cpo_q, float* __restrict__ cpo_s)
{
    __shared__ __align__(16) char smem[34304];
    short* xs = (short*)smem;                    // 32 KB bf16, XOR-16B swizzled
    float* part   = (float*)(smem + 32768);      // [4 waves][64 rows] partial v-dots
    float* av_lds = (float*)(smem + 33792);      // [2][64] softmax coeffs
    short* PL = (short*)smem;                    // aliases xs after pooling reads
    unsigned short* cob = (unsigned short*)(smem + 8192);  // GEMM2 staging (alias)

    const int tid = threadIdx.x;
    const int w = tid >> 6, lane = tid & 63;
    const int lr = lane & 15, g = lane >> 4;
    const int h = w >> 1;                        // head this wave's columns belong to

    // ---- stage 64 rows of x to LDS as bf16 (two halves of 8 float4 in flight) ----
    {
        const float* xb = x + (size_t)blockIdx.x * (64 * 256);
        #pragma unroll
        for (int half = 0; half < 2; ++half) {
            float4 va[4], vb[4];
            #pragma unroll
            for (int k = 0; k < 4; ++k) {
                int u = (half * 4 + k) * 256 + tid;
                const float4* p = (const float4*)(xb + (size_t)u * 8);
                va[k] = p[0]; vb[k] = p[1];
            }
            #pragma unroll
            for (int k = 0; k < 4; ++k) {
                int u = (half * 4 + k) * 256 + tid;
                int row = u >> 5, cu = u & 31;
                s16x8 s;
                s[0] = (short)f2bf(va[k].x); s[1] = (short)f2bf(va[k].y);
                s[2] = (short)f2bf(va[k].z); s[3] = (short)f2bf(va[k].w);
                s[4] = (short)f2bf(vb[k].x); s[5] = (short)f2bf(vb[k].y);
                s[6] = (short)f2bf(vb[k].z); s[7] = (short)f2bf(vb[k].w);
                int byte = row * 512 + ((cu * 16) ^ ((row & 7) << 4));
                *(s16x8*)((char*)xs + byte) = s;
            }
        }
    }
    __syncthreads();

    // ---- GEMM1 (ct-split): ep[rt][i] = sum over this wave's 4 col-tiles of tanh()*v ----
    float ep[4][4];
    #pragma unroll
    for (int rt = 0; rt < 4; ++rt)
        #pragma unroll
        for (int i = 0; i < 4; ++i) ep[rt][i] = 0.f;

    const s16x8* B1 = (const s16x8*)Bsw1;
    const int sw = (lr & 7) << 4;
    #pragma unroll
    for (int p = 0; p < 2; ++p) {
        const int ct0 = w * 4 + p * 2;
        s16x8 b0[8], b1[8];
        #pragma unroll
        for (int kt = 0; kt < 8; ++kt) {
            b0[kt] = B1[(kt * 16 + ct0) * 64 + lane];
            b1[kt] = B1[(kt * 16 + ct0 + 1) * 64 + lane];
        }
        const int jj0 = (w & 1) * 64 + p * 32 + lr;       // in-head col of ct0 for this lane
        const float bb0 = h ? bao[jj0] : bac[jj0];
        const float vv0 = h ? vao[jj0] : vac[jj0];
        const float bb1 = h ? bao[jj0 + 16] : bac[jj0 + 16];
        const float vv1 = h ? vao[jj0 + 16] : vac[jj0 + 16];
        #pragma unroll
        for (int rt = 0; rt < 4; ++rt) {
            char* base = (char*)xs + (rt * 16 + lr) * 512;
            f32x4 acc0 = {0.f, 0.f, 0.f, 0.f}, acc1 = {0.f, 0.f, 0.f, 0.f};
            #pragma unroll
            for (int kt = 0; kt < 8; ++kt) {
                s16x8 a = *(const s16x8*)(base + ((kt * 64 + g * 16) ^ sw));
                acc0 = __builtin_amdgcn_mfma_f32_16x16x32_bf16(a, b0[kt], acc0, 0, 0, 0);
                acc1 = __builtin_amdgcn_mfma_f32_16x16x32_bf16(a, b1[kt], acc1, 0, 0, 0);
            }
            #pragma unroll
            for (int i = 0; i < 4; ++i) {
                float e0 = __expf(2.f * (acc0[i] + bb0));
                float t0 = (e0 - 1.f) * __builtin_amdgcn_rcpf(e0 + 1.f);
                float e1 = __expf(2.f * (acc1[i] + bb1));
                float t1 = (e1 - 1.f) * __builtin_amdgcn_rcpf(e1 + 1.f);
                ep[rt][i] += t0 * vv0 + t1 * vv1;
            }
        }
    }

    // reduce partial v-dots over the 16 col-lanes, publish per (wave,row)
    #pragma unroll
    for (int rt = 0; rt < 4; ++rt)
        #pragma unroll
        for (int i = 0; i < 4; ++i) {
            float v = ep[rt][i];
            v += __shfl_xor(v, 1); v += __shfl_xor(v, 2);
            v += __shfl_xor(v, 4); v += __shfl_xor(v, 8);
            ep[rt][i] = v;
        }
    if (lr == 0) {
        #pragma unroll
        for (int rt = 0; rt < 4; ++rt)
            #pragma unroll
            for (int i = 0; i < 4; ++i)
                part[w * 64 + rt * 16 + g * 4 + i] = ep[rt][i];
    }
    __syncthreads();

    // ---- combine partials + softmax coefficients (threads 0..127: one per (head,row)) ----
    if (tid < 128) {
        int hh = tid >> 6, row = tid & 63, nb = row & ~7;
        float ee[8];
        #pragma unroll
        for (int u = 0; u < 8; ++u)
            ee[u] = part[hh * 128 + nb + u] + part[hh * 128 + 64 + nb + u];
        float m = -1e30f;
        #pragma unroll
        for (int u = 0; u < 8; ++u) m = fmaxf(m, ee[u]);
        float s = 0.f;
        #pragma unroll
        for (int u = 0; u < 8; ++u) s += __expf(ee[u] - m);
        av_lds[hh * 64 + row] = __expf(ee[row & 7] - m) * __builtin_amdgcn_rcpf(s);
    }
    __syncthreads();

    // ---- pooling from LDS (reads xs), results held in registers ----
    float accp[2][4][2];
    const int d2 = tid & 127;          // col pair (cols 2*d2, 2*d2+1)
    const int nb = (tid >> 7) * 4;     // node base (0 or 4)
    {
        #pragma unroll
        for (int hh = 0; hh < 2; ++hh)
            #pragma unroll
            for (int nn = 0; nn < 4; ++nn) { accp[hh][nn][0] = 0.f; accp[hh][nn][1] = 0.f; }
        #pragma unroll
        for (int nn = 0; nn < 4; ++nn) {
            const int n = nb + nn;
            #pragma unroll
            for (int t = 0; t < 8; ++t) {
                int row = n * 8 + t;
                unsigned u = *(const unsigned*)((char*)xs + row * 512 + ((d2 * 4) ^ (t << 4)));
                float lo = bf2f((unsigned short)(u & 0xffff));
                float hi = bf2f((unsigned short)(u >> 16));
                float a0 = av_lds[row], a1 = av_lds[64 + row];
                accp[0][nn][0] = fmaf(a0, lo, accp[0][nn][0]);
                accp[0][nn][1] = fmaf(a0, hi, accp[0][nn][1]);
                accp[1][nn][0] = fmaf(a1, lo, accp[1][nn][0]);
                accp[1][nn][1] = fmaf(a1, hi, accp[1][nn][1]);
            }
        }
    }
    __syncthreads();   // all xs reads done; safe to overwrite with PL

    // ---- write pooled bf16 pairs into PL (aliases xs) in A-fragment layout ----
    {
        int col = d2 * 2;
        int kt = col >> 5, gg = (col >> 3) & 3, jp = col & 7;
        #pragma unroll
        for (int hh = 0; hh < 2; ++hh)
            #pragma unroll
            for (int nn = 0; nn < 4; ++nn) {
                int n = nb + nn;
                unsigned pv = (unsigned)f2bf(accp[hh][nn][0]) | ((unsigned)f2bf(accp[hh][nn][1]) << 16);
                int sidx = (((hh * 8 + kt) * 4 + gg) * 8 + n) * 8 + jp;
                *(unsigned*)((char*)PL + sidx * 2) = pv;
            }
    }
    __syncthreads();

    // ---- GEMM2: cob[8 nodes][256] = pooled_{c|o} @ [Wc|Wo] ----
    {
        const int head = w >> 1;           // waves 0,1 -> c cols, 2,3 -> o cols
        s16x8 a2[8];
        #pragma unroll
        for (int kt = 0; kt < 8; ++kt) {
            int sidx = (((head * 8 + kt) * 4 + g) * 8 + (lr & 7)) * 8;
            a2[kt] = *(const s16x8*)((char*)PL + sidx * 2);
        }
        const s16x8* B2 = (const s16x8*)Bsw2;
        #pragma unroll
        for (int c2 = 0; c2 < 4; ++c2) {
            int ct = w * 4 + c2;
            f32x4 acc = {0.f, 0.f, 0.f, 0.f};
            #pragma unroll
            for (int kt = 0; kt < 8; ++kt)
                acc = __builtin_amdgcn_mfma_f32_16x16x32_bf16(a2[kt], B2[(kt * 16 + ct) * 64 + lane], acc, 0, 0, 0);
            if (g < 2) {
                int col = head * 128 + (ct & 7) * 16 + lr;
                #pragma unroll
                for (int i = 0; i < 4; ++i) {
                    int node = g * 4 + i;
                    cob[node * 256 + col] = f2bf(acc[i]);
                }
            }
        }
    }
    __syncthreads();

    // ---- per-row int8 quantize + coalesced bf16/int8/scale writes ----
    {
        const int n0 = blockIdx.x * 8;
        const int row = tid >> 5;          // 0..7 (32 threads per row)
        s16x8 cb = *(const s16x8*)&cob[row * 256 + (tid & 31) * 8];
        float v[8]; float m = 0.f;
        #pragma unroll
        for (int j = 0; j < 8; ++j) { v[j] = bf2f((unsigned short)cb[j]); m = fmaxf(m, fabsf(v[j])); }
        #pragma unroll
        for (int d = 1; d < 32; d <<= 1) m = fmaxf(m, __shfl_xor(m, d));
        float inv = (m > 0.f) ? 127.f / m : 0.f;
        s8x8 q;
        #pragma unroll
        for (int j = 0; j < 8; ++j) q[j] = (char)__float2int_rn(v[j] * inv);
        const size_t base = (size_t)n0 * 256;
        ((s16x8*)(cpo_bf + base))[tid] = cb;
        ((s8x8*)(cpo_q + base))[tid] = q;
        if ((tid & 31) == 0) cpo_s[n0 + row] = m * (1.f / 127.f);
    }
}

// ---------------- CSR scan + fill ----------------
__global__ __launch_bounds__(1024) void k_scan(const int* __restrict__ counts, int* __restrict__ starts) {
    __shared__ int sdata[1024];
    __shared__ int s_running;
    if (threadIdx.x == 0) s_running = 0;
    __syncthreads();
    const int nChunks = (NN + 1023) / 1024;
    for (int c = 0; c < nChunks; ++c) {
        int i = c * 1024 + threadIdx.x;
        int v = (i < NN) ? counts[i] : 0;
        sdata[threadIdx.x] = v;
        __syncthreads();
        for (int off = 1; off < 1024; off <<= 1) {
            int tv = (threadIdx.x >= off) ? sdata[threadIdx.x - off] : 0;
            __syncthreads();
            sdata[threadIdx.x] += tv;
            __syncthreads();
        }
        int incl = sdata[threadIdx.x];
        int run = s_running;
        __syncthreads();
        if (i < NN) starts[i] = run + incl - v;
        if (threadIdx.x == 1023) s_running = run + incl;
        __syncthreads();
    }
    if (threadIdx.x == 0) starts[NN] = s_running;
}

__global__ void k_fill(const int* __restrict__ src, const int* __restrict__ dst,
                       const float* __restrict__ w, const int* __restrict__ starts,
                       int* __restrict__ cursor, Edge* __restrict__ edges) {
    int e = blockIdx.x * 256 + threadIdx.x;
    if (e >= EE) return;
    int d = dst[e];
    int pos = atomicAdd(&cursor[d], 1);
    Edge ed; ed.s = src[e]; ed.w = w[e];
    edges[starts[d] + pos] = ed;
}

// ---------------- GNN hops: half-wave edge parallel, int8 row gathers ----------------
// wave = node; lanes 0-31 even edges, 32-63 odd edges; lane covers 8 cols (8 B int8).
__global__ __launch_bounds__(256) void k_hop1(
    const char* __restrict__ cpo_q, const float* __restrict__ cpo_s,
    const int* __restrict__ starts, const Edge* __restrict__ edges,
    char* __restrict__ g1_q, float* __restrict__ g1_s)
{
    const int lane = threadIdx.x & 63;
    const int node = blockIdx.x * 4 + (threadIdx.x >> 6);
    const int half = lane >> 5;
    const int c0 = (lane & 31) * 8;
    const int s0 = starts[node];
    const int s1 = starts[node + 1];
    float acc[8] = {0.f, 0.f, 0.f, 0.f, 0.f, 0.f, 0.f, 0.f};
    int i = s0 + half;
    for (; i + 6 < s1; i += 8) {
        Edge e0 = edges[i], e1 = edges[i + 2], e2 = edges[i + 4], e3 = edges[i + 6];
        s8x8 v0 = *(const s8x8*)&cpo_q[(size_t)e0.s * 256 + c0];
        s8x8 v1 = *(const s8x8*)&cpo_q[(size_t)e1.s * 256 + c0];
        s8x8 v2 = *(const s8x8*)&cpo_q[(size_t)e2.s * 256 + c0];
        s8x8 v3 = *(const s8x8*)&cpo_q[(size_t)e3.s * 256 + c0];
        float w0 = e0.w * cpo_s[e0.s], w1 = e1.w * cpo_s[e1.s];
        float w2 = e2.w * cpo_s[e2.s], w3 = e3.w * cpo_s[e3.s];
        #pragma unroll
        for (int j = 0; j < 8; ++j) {
            acc[j] = fmaf(w0, (float)v0[j],
                     fmaf(w1, (float)v1[j],
                     fmaf(w2, (float)v2[j],
                     fmaf(w3, (float)v3[j], acc[j]))));
        }
    }
    for (; i < s1; i += 2) {
        Edge e0 = edges[i];
        s8x8 v0 = *(const s8x8*)&cpo_q[(size_t)e0.s * 256 + c0];
        float w0 = e0.w * cpo_s[e0.s];
        #pragma unroll
        for (int j = 0; j < 8; ++j)
            acc[j] = fmaf(w0, (float)v0[j], acc[j]);
    }
    #pragma unroll
    for (int j = 0; j < 8; ++j) acc[j] += __shfl_xor(acc[j], 32);
    float m = 0.f;
    #pragma unroll
    for (int j = 0; j < 8; ++j) m = fmaxf(m, fabsf(acc[j]));
    #pragma unroll
    for (int d = 1; d < 32; d <<= 1) m = fmaxf(m, __shfl_xor(m, d));
    if (half == 0) {
        float inv = (m > 0.f) ? 127.f / m : 0.f;
        s8x8 q;
        #pragma unroll
        for (int j = 0; j < 8; ++j) q[j] = (char)__float2int_rn(acc[j] * inv);
        *(s8x8*)&g1_q[(size_t)node * 256 + c0] = q;
        if (lane == 0) g1_s[node] = m * (1.f / 127.f);
    }
}

__global__ __launch_bounds__(256) void k_hop2(
    const char* __restrict__ g1_q, const float* __restrict__ g1_s,
    const unsigned short* __restrict__ cpo_bf,
    const float* __restrict__ bc, const float* __restrict__ bo,
    const int* __restrict__ starts, const Edge* __restrict__ edges,
    float* __restrict__ out)
{
    const int lane = threadIdx.x & 63;
    const int node = blockIdx.x * 4 + (threadIdx.x >> 6);
    const int half = lane >> 5;
    const int c0 = (lane & 31) * 8;
    const int s0 = starts[node];
    const int s1 = starts[node + 1];
    float acc[8] = {0.f, 0.f, 0.f, 0.f, 0.f, 0.f, 0.f, 0.f};
    int i = s0 + half;
    for (; i + 6 < s1; i += 8) {
        Edge e0 = edges[i], e1 = edges[i + 2], e2 = edges[i + 4], e3 = edges[i + 6];
        s8x8 v0 = *(const s8x8*)&g1_q[(size_t)e0.s * 256 + c0];
        s8x8 v1 = *(const s8x8*)&g1_q[(size_t)e1.s * 256 + c0];
        s8x8 v2 = *(const s8x8*)&g1_q[(size_t)e2.s * 256 + c0];
        s8x8 v3 = *(const s8x8*)&g1_q[(size_t)e3.s * 256 + c0];
        float w0 = e0.w * g1_s[e0.s], w1 = e1.w * g1_s[e1.s];
        float w2 = e2.w * g1_s[e2.s], w3 = e3.w * g1_s[e3.s];
        #pragma unroll
        for (int j = 0; j < 8; ++j) {
            acc[j] = fmaf(w0, (float)v0[j],
                     fmaf(w1, (float)v1[j],
                     fmaf(w2, (float)v2[j],
                     fmaf(w3, (float)v3[j], acc[j]))));
        }
    }
    for (; i < s1; i += 2) {
        Edge e0 = edges[i];
        s8x8 v0 = *(const s8x8*)&g1_q[(size_t)e0.s * 256 + c0];
        float w0 = e0.w * g1_s[e0.s];
        #pragma unroll
        for (int j = 0; j < 8; ++j)
            acc[j] = fmaf(w0, (float)v0[j], acc[j]);
    }
    #pragma unroll
    for (int j = 0; j < 8; ++j) acc[j] += __shfl_xor(acc[j], 32);
    if (half == 0) {
        s16x8 cv = *(const s16x8*)&cpo_bf[(size_t)node * 256 + c0];
        float r[8];
        if (c0 < 128) {
            #pragma unroll
            for (int j = 0; j < 8; ++j)
                r[j] = acc[j] + bf2f((unsigned short)cv[j]) + bc[c0 + j];
            float4* o4 = (float4*)&out[(size_t)node * 128 + c0];
            o4[0] = make_float4(r[0], r[1], r[2], r[3]);
            o4[1] = make_float4(r[4], r[5], r[6], r[7]);
        } else {
            #pragma unroll
            for (int j = 0; j < 8; ++j)
                r[j] = fmaxf(acc[j] + bf2f((unsigned short)cv[j]) + bo[c0 - 128 + j], 0.f);
            float4* o4 = (float4*)&out[(size_t)NN * 128 + (size_t)node * 128 + (c0 - 128)];
            o4[0] = make_float4(r[0], r[1], r[2], r[3]);
            o4[1] = make_float4(r[4], r[5], r[6], r[7]);
        }
    }
}

// ---------------- launch ----------------
extern "C" void kernel_launch(void* const* d_in, const int* in_sizes, int n_in,
                              void* d_out, int out_size, void* d_ws, size_t ws_size,
                              hipStream_t stream)
{
    const float* x   = (const float*)d_in[0];
    const int*   ei  = (const int*)d_in[1];
    const float* ew  = (const float*)d_in[2];
    const float* Wac = (const float*)d_in[3];
    const float* bac = (const float*)d_in[4];
    const float* vac = (const float*)d_in[5];
    const float* Wao = (const float*)d_in[6];
    const float* bao = (const float*)d_in[7];
    const float* vao = (const float*)d_in[8];
    const float* Wc  = (const float*)d_in[9];
    const float* bc  = (const float*)d_in[10];
    const float* Wo  = (const float*)d_in[11];
    const float* bo  = (const float*)d_in[12];
    float* out = (float*)d_out;

    char* ws = (char*)d_ws;
    unsigned short* cpo_bf = (unsigned short*)(ws + 0);         // [N][256] bf16 = 25.6 MB
    char*  cpo_q  = (char*)(ws + 25600000);      // [N][256] int8 = 12.8 MB
    float* cpo_s  = (float*)(ws + 38400000);     // [N] scales, 200 KB
    char*  g1_q   = (char*)(ws + 38600192);      // [N][256] int8 = 12.8 MB
    float* g1_s   = (float*)(ws + 51400192);     // [N] scales, 200 KB
    short* Bsw1   = (short*)(ws + 51600384);     // 128 KB
    short* Bsw2   = (short*)(ws + 51731456);     // 128 KB
    int*   counts = (int*)(ws + 102400000);      // N ints
    int*   cursor = (int*)(ws + 102600064);      // N ints (adjacent -> one memset)
    int*   starts = (int*)(ws + 102800128);      // N+1 ints
    Edge*  edges  = (Edge*)(ws + 103000192);     // E * 8 B = 6.4 MB, end ~109.4 MB

    const int* src = ei;
    const int* dst = ei + EE;

    hipMemsetAsync(counts, 0, 400128, stream);   // counts + cursor in one shot

    k_pc<<<64 + (EE + 255) / 256, 256, 0, stream>>>(Wac, Wao, Wc, Wo, Bsw1, Bsw2, dst, counts);
    k_scan<<<1, 1024, 0, stream>>>(counts, starts);
    k_fill<<<(EE + 255) / 256, 256, 0, stream>>>(src, dst, ew, starts, cursor, edges);
    k_att5<<<NN / 8, 256, 0, stream>>>(x, Bsw1, Bsw2, bac, vac, bao, vao, cpo_bf, cpo_q, cpo_s);
    k_hop1<<<NN / 4, 256, 0, stream>>>(cpo_q, cpo_s, starts, edges, g1_q, g1_s);
    k_hop2<<<NN / 4, 256, 0, stream>>>(g1_q, g1_s, cpo_bf, bc, bo, starts, edges, out);
}